// Round 12
// baseline (42.687 us; speedup 1.0000x reference)
//
#include <hip/hip_runtime.h>

// Involution fused kernels for MI355X (gfx950).
// x: (4,256,56,56) f32, w1: (64,256), bn(64), w2: (784,64), b2: (784)
// out: (4,256,56,56) f32
// ws: ybf16 [4][3136][64] | wprep bf16 [16][64][64] | b2pad f32 [16][64] | w1bf bf16 [64][256]

#define HW    3136
#define WIDE  56
#define C_IN  256
#define CR    64
#define GC    16
#define KK    49
#define BN_EPS 1e-5f

typedef __attribute__((ext_vector_type(8))) short short8;
typedef __attribute__((ext_vector_type(4))) float f32x4;
typedef __attribute__((ext_vector_type(2))) unsigned int u32x2;

__device__ __forceinline__ unsigned short f2bf(float f) {
    unsigned u = __float_as_uint(f);
    return (unsigned short)((u + 0x7FFFu + ((u >> 16) & 1u)) >> 16);   // RNE
}

// ---- Prep: w1bf[o][c] bf16; wprep[g][k][c] bf16 (k>=49 zero); b2pad[g][k] f32 ----
__global__ __launch_bounds__(256) void prep_kernel(
    const float* __restrict__ w1, const float* __restrict__ w2,
    const float* __restrict__ b2,
    unsigned short* __restrict__ w1bf, unsigned short* __restrict__ wprep,
    float* __restrict__ b2pad)
{
    const int t = blockIdx.x * 256 + threadIdx.x;   // 0..65535
    if (t < 16384) {                                // w1bf: same [o][c] layout
        w1bf[t] = f2bf(w1[t]);
    }
    {                                               // wprep: g=t>>12, k=(t>>6)&63, c=t&63
        const int g = t >> 12, k = (t >> 6) & 63, c = t & 63;
        wprep[t] = (k < KK) ? f2bf(w2[(size_t)(g * KK + k) * CR + c]) : (unsigned short)0;
    }
    if (t < 1024) {                                 // b2pad
        const int g = t >> 6, k = t & 63;
        b2pad[t] = (k < KK) ? b2[g * KK + k] : 0.f;
    }
}

// LDS xs[px][c] bf16, XOR-swizzled: byte = (px*512 + c*2) ^ ((px&7)<<4).
__device__ __forceinline__ int xs_byte(int px, int c) {
    return ((px << 9) + (c << 1)) ^ ((px & 7) << 4);
}

// ---- Kernel 1: y = relu(bn(w1 @ x)) -> bf16 [b][px][c], via MFMA (R11) ----
__global__ __launch_bounds__(256) void conv1_bn_relu(
    const float* __restrict__ x, const unsigned short* __restrict__ w1bf,
    const float* __restrict__ gamma, const float* __restrict__ beta,
    const float* __restrict__ mean, const float* __restrict__ var,
    unsigned short* __restrict__ ybf)
{
    __shared__ unsigned short xs[64 * 256];   // 32 KB

    const int t    = threadIdx.x;
    const int lane = t & 63;
    const int q    = __builtin_amdgcn_readfirstlane(t >> 6);  // wave 0..3
    const int tile = blockIdx.x;              // 0..195
    const int b    = tile / 49;
    const int hw0  = (tile - b * 49) * 64;

    // ---- stage x[b][c][hw0+lane] -> xs[lane][c] ----
    {
        const int px = lane;
        const int cb = q * 64;
        const float* __restrict__ xb = x + ((size_t)b * C_IN + cb) * HW + hw0 + px;
#pragma unroll
        for (int i = 0; i < 8; ++i) {
            short8 pk;
#pragma unroll
            for (int j = 0; j < 8; ++j)
                pk[j] = (short)f2bf(xb[(size_t)(i * 8 + j) * HW]);
            *(short8*)((char*)xs + xs_byte(px, cb + i * 8)) = pk;
        }
    }
    __syncthreads();

    // ---- MFMA: y[o][px] for px-quadrant q ----
    const int l15 = lane & 15;
    const int lg  = lane >> 4;
    const int px  = q * 16 + l15;

    f32x4 acc[4];
#pragma unroll
    for (int mt = 0; mt < 4; ++mt) acc[mt] = (f32x4){0.f, 0.f, 0.f, 0.f};

#pragma unroll
    for (int kk = 0; kk < 8; ++kk) {
        const short8 Bf = *(const short8*)((const char*)xs + xs_byte(px, kk * 32 + lg * 8));
#pragma unroll
        for (int mt = 0; mt < 4; ++mt) {
            const short8 Af = *(const short8*)(w1bf + (mt * 16 + l15) * C_IN + kk * 32 + lg * 8);
            acc[mt] = __builtin_amdgcn_mfma_f32_16x16x32_bf16(Af, Bf, acc[mt], 0, 0, 0);
        }
    }

    // ---- BN + ReLU + pack; D: col=l15 -> px, row=lg*4+r -> o ----
#pragma unroll
    for (int mt = 0; mt < 4; ++mt) {
        const int o0 = mt * 16 + lg * 4;
        const f32x4 ga = *(const f32x4*)(gamma + o0);
        const f32x4 be = *(const f32x4*)(beta + o0);
        const f32x4 mn = *(const f32x4*)(mean + o0);
        const f32x4 va = *(const f32x4*)(var + o0);
        unsigned short o4[4];
#pragma unroll
        for (int r = 0; r < 4; ++r) {
            const float sc = ga[r] * rsqrtf(va[r] + BN_EPS);
            const float sh = be[r] - mn[r] * sc;
            o4[r] = f2bf(fmaxf(acc[mt][r] * sc + sh, 0.f));
        }
        u32x2 pk;
        pk.x = (unsigned)o4[0] | ((unsigned)o4[1] << 16);
        pk.y = (unsigned)o4[2] | ((unsigned)o4[3] << 16);
        *(u32x2*)(ybf + ((size_t)(b * HW + hw0 + px)) * 64 + o0) = pk;
    }
}

// ---- Kernel 2: MFMA conv2 + vectorized involution (R5 body). ----
// GRID CHANGE ONLY: 1D grid 3136, (b,g)-pinned XCD swizzle. bid = slot*8 +
// xcd (dispatch round-robins bid%8 across XCDs); bg = xcd*8 + slot/49,
// tile = slot%49. All 49 tiles of one (b,g) execute consecutively on ONE
// XCD -> per-XCD L2 working set = 1-2 x-slices (~400KB << 4MB), so phase
// 2's ~270MB of window reads are L2-hits instead of L3, and each x plane
// is HBM-fetched once.
__global__ __launch_bounds__(64) void conv2_involution(
    const float* __restrict__ x, const unsigned short* __restrict__ ybf,
    const unsigned short* __restrict__ wprep, const float* __restrict__ b2pad,
    float* __restrict__ out)
{
    __shared__ float kw_lds[64 * 64];   // [tap][px], 16 KB

    const int bid  = blockIdx.x;                 // 0..3135
    const int xcd  = bid & 7;
    const int slot = bid >> 3;                   // 0..391
    const int bg   = xcd * 8 + slot / 49;        // 0..63
    const int tile = slot - (slot / 49) * 49;    // 0..48
    const int g    = bg & 15;
    const int b    = bg >> 4;

    const int tid  = threadIdx.x;
    const int l15  = tid & 15;
    const int lg   = tid >> 4;

    // ---- Phase 1: kw = W2g @ y  (per-pixel 64-tap kernels) ----
    {
        short8 Bf[4][2], Af[4][2];
#pragma unroll
        for (int ct = 0; ct < 4; ++ct) {
            const int hwp = tile * 64 + ct * 16 + l15;
            const unsigned short* yb = ybf + ((size_t)(b * HW + hwp)) * 64 + lg * 8;
            Bf[ct][0] = *(const short8*)(yb);
            Bf[ct][1] = *(const short8*)(yb + 32);
        }
#pragma unroll
        for (int rt = 0; rt < 4; ++rt) {
            const unsigned short* ar = wprep + g * 4096 + (rt * 16 + l15) * 64 + lg * 8;
            Af[rt][0] = *(const short8*)(ar);
            Af[rt][1] = *(const short8*)(ar + 32);
        }
        f32x4 acc[4][4];
#pragma unroll
        for (int ct = 0; ct < 4; ++ct)
#pragma unroll
            for (int rt = 0; rt < 4; ++rt) {
                acc[ct][rt] = (f32x4){0.f, 0.f, 0.f, 0.f};
                acc[ct][rt] = __builtin_amdgcn_mfma_f32_16x16x32_bf16(Af[rt][0], Bf[ct][0], acc[ct][rt], 0, 0, 0);
                acc[ct][rt] = __builtin_amdgcn_mfma_f32_16x16x32_bf16(Af[rt][1], Bf[ct][1], acc[ct][rt], 0, 0, 0);
            }

        float bias[4][4];
#pragma unroll
        for (int rt = 0; rt < 4; ++rt)
#pragma unroll
            for (int r = 0; r < 4; ++r)
                bias[rt][r] = b2pad[g * 64 + rt * 16 + lg * 4 + r];

#pragma unroll
        for (int ct = 0; ct < 4; ++ct) {
            const int pxc = ct * 16 + l15;
            const int hwp = tile * 64 + pxc;
            const int hp  = hwp / WIDE;
            const int wp  = hwp - hp * WIDE;
#pragma unroll
            for (int rt = 0; rt < 4; ++rt)
#pragma unroll
                for (int r = 0; r < 4; ++r) {
                    const int k  = rt * 16 + lg * 4 + r;
                    const int i7 = k / 7, j7 = k - i7 * 7;
                    const int rr = hp + i7 - 3, cc = wp + j7 - 3;
                    const bool valid = (k < KK) & (rr >= 0) & (rr < WIDE) &
                                       (cc >= 0) & (cc < WIDE);
                    kw_lds[k * 64 + pxc] = valid ? (acc[ct][rt][r] + bias[rt][r]) : 0.f;
                }
        }
    }
    __syncthreads();

    // ---- Phase 2: involution, 4 px x 4 ch per thread ----
    const int pg   = tid & 15;
    const int cq   = tid >> 4;
    const int hw4  = tile * 64 + pg * 4;         // 4-aligned flat pixel base
    const int hrow = hw4 / WIDE;
    const int hcol = hw4 - hrow * WIDE;          // 4-aligned (56 % 4 == 0)

    const float* bp[4];
#pragma unroll
    for (int c = 0; c < 4; ++c)
        bp[c] = x + ((size_t)b * C_IN + g * GC + cq * 4 + c) * HW;

    float acc2[4][4];   // [ch][px]
#pragma unroll
    for (int c = 0; c < 4; ++c)
#pragma unroll
        for (int p = 0; p < 4; ++p) acc2[c][p] = 0.f;

#pragma unroll
    for (int i = 0; i < 7; ++i) {
        const int rc    = min(max(hrow + i - 3, 0), WIDE - 1);  // v_med3
        const int basef = rc * WIDE + hcol;
        const int i0 = max(basef - 4, 0);
        const int i2 = min(basef + 4, HW - 4);

        float win[4][12];
#pragma unroll
        for (int c = 0; c < 4; ++c) {
            const f32x4 A0 = *(const f32x4*)(bp[c] + i0);
            const f32x4 A1 = *(const f32x4*)(bp[c] + basef);
            const f32x4 A2 = *(const f32x4*)(bp[c] + i2);
#pragma unroll
            for (int e = 0; e < 4; ++e) {
                win[c][e]     = A0[e];
                win[c][e + 4] = A1[e];
                win[c][e + 8] = A2[e];
            }
        }
#pragma unroll
        for (int jj = 0; jj < 7; ++jj) {
            const f32x4 kw4 = *(const f32x4*)&kw_lds[(i * 7 + jj) * 64 + pg * 4];
#pragma unroll
            for (int c = 0; c < 4; ++c)
#pragma unroll
                for (int p = 0; p < 4; ++p)
                    acc2[c][p] += kw4[p] * win[c][p + jj + 1];   // e = 4+(p+jj-3)
        }
    }

#pragma unroll
    for (int c = 0; c < 4; ++c) {
        f32x4 st;
#pragma unroll
        for (int p = 0; p < 4; ++p) st[p] = acc2[c][p];
        *(f32x4*)(out + ((size_t)b * C_IN + g * GC + cq * 4 + c) * HW + hw4) = st;
    }
}

extern "C" void kernel_launch(void* const* d_in, const int* in_sizes, int n_in,
                              void* d_out, int out_size, void* d_ws, size_t ws_size,
                              hipStream_t stream) {
    const float* x     = (const float*)d_in[0];
    const float* w1    = (const float*)d_in[1];
    const float* gamma = (const float*)d_in[2];
    const float* beta  = (const float*)d_in[3];
    const float* mean  = (const float*)d_in[4];
    const float* var   = (const float*)d_in[5];
    const float* w2    = (const float*)d_in[6];
    const float* b2    = (const float*)d_in[7];
    float* out = (float*)d_out;

    char* ws = (char*)d_ws;
    unsigned short* ybf   = (unsigned short*)(ws);             // 1,605,632 B
    unsigned short* wprep = (unsigned short*)(ws + 1605632);   //   131,072 B
    float*          b2pad = (float*)(ws + 1736704);            //     4,096 B
    unsigned short* w1bf  = (unsigned short*)(ws + 1740800);   //    32,768 B

    prep_kernel<<<dim3(256), dim3(256), 0, stream>>>(w1, w2, b2, w1bf, wprep, b2pad);
    conv1_bn_relu<<<dim3(196), dim3(256), 0, stream>>>(x, w1bf, gamma, beta, mean, var, ybf);
    conv2_involution<<<dim3(3136), dim3(64), 0, stream>>>(x, ybf, wprep, b2pad, out);
}